// Round 1
// baseline (3416.723 us; speedup 1.0000x reference)
//
#include <hip/hip_runtime.h>
#include <hip/hip_bf16.h>
#include <math.h>

#define N_NODES 100000
#define F_IN    500
#define HID     64
#define NCLS    47
#define CP      48      // padded row stride for propagation buffers (192B = 3 lines)
#define N_EDGE  3200000
#define K_PROP  10

typedef _Float16 v8h  __attribute__((ext_vector_type(8)));
typedef float    v4f  __attribute__((ext_vector_type(4)));

// ---------------------------------------------------------------------------
// GEMM1: h[N,64] = relu(x[N,500] @ W1[500,64] + b1), f16 output for GEMM2.
// Block = 256 thr (4 waves). Block tile 128 rows x 64 cols, BK=32 (K padded
// to 512 with zeros). Wave w: rows [w*32, w*32+32), 2x4 mfma_16x16x32_f16.
// ---------------------------------------------------------------------------
__global__ __launch_bounds__(256) void gemm1_relu(
    const float* __restrict__ x, const float* __restrict__ W1,
    const float* __restrict__ b1, _Float16* __restrict__ h)
{
  __shared__ _Float16 xa[128][40];   // stride 40 f16 = 80B: 16B-aligned frags, 2-way banks
  __shared__ _Float16 wb[64][40];    // W1 tile transposed: wb[col][k]
  const int tid  = threadIdx.x;
  const int lane = tid & 63;
  const int wv   = tid >> 6;
  const int l15  = lane & 15;
  const int quad = lane >> 4;
  const int row0 = blockIdx.x * 128;

  v4f acc[2][4] = {};

  for (int k0 = 0; k0 < F_IN; k0 += 32) {
    // stage x tile: 128 rows x 32 k  (1024 float4 over 256 threads)
    #pragma unroll
    for (int i = 0; i < 4; ++i) {
      int f = tid + i * 256;
      int r = f >> 3, q = f & 7;
      int gr = row0 + r;
      int kk = k0 + q * 4;
      float v0 = 0.f, v1 = 0.f, v2 = 0.f, v3 = 0.f;
      if (gr < N_NODES) {
        if (kk + 3 < F_IN) {
          const float4 v = *(const float4*)(x + (size_t)gr * F_IN + kk);
          v0 = v.x; v1 = v.y; v2 = v.z; v3 = v.w;
        } else {
          const float* xp = x + (size_t)gr * F_IN;
          if (kk + 0 < F_IN) v0 = xp[kk + 0];
          if (kk + 1 < F_IN) v1 = xp[kk + 1];
          if (kk + 2 < F_IN) v2 = xp[kk + 2];
          if (kk + 3 < F_IN) v3 = xp[kk + 3];
        }
      }
      _Float16* p = &xa[r][q * 4];
      p[0] = (_Float16)v0; p[1] = (_Float16)v1;
      p[2] = (_Float16)v2; p[3] = (_Float16)v3;
    }
    // stage W1 tile transposed: wb[c][k] = W1[k0+k][c]  (512 float4-chunks)
    #pragma unroll
    for (int i = 0; i < 2; ++i) {
      int f = tid + i * 256;
      int k = f >> 4, c4 = (f & 15) * 4;
      int gk = k0 + k;
      float4 v = make_float4(0.f, 0.f, 0.f, 0.f);
      if (gk < F_IN) v = *(const float4*)(W1 + (size_t)gk * HID + c4);
      wb[c4 + 0][k] = (_Float16)v.x; wb[c4 + 1][k] = (_Float16)v.y;
      wb[c4 + 2][k] = (_Float16)v.z; wb[c4 + 3][k] = (_Float16)v.w;
    }
    __syncthreads();
    const int m0 = wv * 32;
    // A frag: A[m=lane&15][k=quad*8+j] ; B frag: B[k=quad*8+j][n=lane&15]
    v8h a0 = *(const v8h*)&xa[m0 + l15][quad * 8];
    v8h a1 = *(const v8h*)&xa[m0 + 16 + l15][quad * 8];
    #pragma unroll
    for (int nt = 0; nt < 4; ++nt) {
      v8h b = *(const v8h*)&wb[nt * 16 + l15][quad * 8];
      acc[0][nt] = __builtin_amdgcn_mfma_f32_16x16x32_f16(a0, b, acc[0][nt], 0, 0, 0);
      acc[1][nt] = __builtin_amdgcn_mfma_f32_16x16x32_f16(a1, b, acc[1][nt], 0, 0, 0);
    }
    __syncthreads();
  }
  // epilogue: C/D layout col=lane&15, row=quad*4+reg
  const int m0 = wv * 32;
  float b1v[4];
  #pragma unroll
  for (int nt = 0; nt < 4; ++nt) b1v[nt] = b1[nt * 16 + l15];
  #pragma unroll
  for (int mi = 0; mi < 2; ++mi)
    #pragma unroll
    for (int r = 0; r < 4; ++r) {
      int grow = row0 + m0 + mi * 16 + quad * 4 + r;
      if (grow < N_NODES) {
        #pragma unroll
        for (int nt = 0; nt < 4; ++nt) {
          float v = fmaxf(acc[mi][nt][r] + b1v[nt], 0.f);
          h[(size_t)grow * HID + nt * 16 + l15] = (_Float16)v;
        }
      }
    }
}

// ---------------------------------------------------------------------------
// GEMM2 fused: z = h @ W2 + b2 ; out_ls = log_softmax(z) ; out_hid = temp0*z ;
// cur = z (stride CP). Block tile 128 rows x 64 cols (cols 47..63 zero-padded).
// ---------------------------------------------------------------------------
__global__ __launch_bounds__(256) void gemm2_fused(
    const _Float16* __restrict__ h, const float* __restrict__ W2,
    const float* __restrict__ b2, const float* __restrict__ temp,
    float* __restrict__ out_ls, float* __restrict__ out_hid,
    float* __restrict__ cur)
{
  __shared__ _Float16 ha[128][72];   // 144B rows: 16B-aligned frags
  __shared__ _Float16 wb[64][72];    // W2 transposed+padded: wb[n][k]
  __shared__ float b2s[64];
  const int tid  = threadIdx.x;
  const int lane = tid & 63;
  const int wv   = tid >> 6;
  const int l15  = lane & 15;
  const int quad = lane >> 4;
  const int row0 = blockIdx.x * 128;

  for (int i = tid; i < 64 * 72; i += 256) ((_Float16*)wb)[i] = (_Float16)0.f;
  if (tid < 64) b2s[tid] = (tid < NCLS) ? b2[tid] : 0.f;
  __syncthreads();
  for (int i = tid; i < HID * NCLS; i += 256) {
    int k = i / NCLS, n = i % NCLS;
    wb[n][k] = (_Float16)W2[i];
  }
  // stage h tile (f16x4 chunks)
  const unsigned short* hu = (const unsigned short*)h;
  #pragma unroll
  for (int i = 0; i < 8; ++i) {
    int f = tid + i * 256;
    int r = f >> 4, q = (f & 15) * 4;
    int gr = row0 + r;
    ushort4 v = make_ushort4(0, 0, 0, 0);
    if (gr < N_NODES) v = *(const ushort4*)(hu + (size_t)gr * HID + q);
    *(ushort4*)((unsigned short*)&ha[r][0] + q) = v;
  }
  __syncthreads();

  const int m0 = wv * 32;
  v4f acc[2][4] = {};
  #pragma unroll
  for (int ks = 0; ks < 2; ++ks) {
    v8h a0 = *(const v8h*)&ha[m0 + l15][ks * 32 + quad * 8];
    v8h a1 = *(const v8h*)&ha[m0 + 16 + l15][ks * 32 + quad * 8];
    #pragma unroll
    for (int nt = 0; nt < 4; ++nt) {
      v8h b = *(const v8h*)&wb[nt * 16 + l15][ks * 32 + quad * 8];
      acc[0][nt] = __builtin_amdgcn_mfma_f32_16x16x32_f16(a0, b, acc[0][nt], 0, 0, 0);
      acc[1][nt] = __builtin_amdgcn_mfma_f32_16x16x32_f16(a1, b, acc[1][nt], 0, 0, 0);
    }
  }

  const float t0 = temp[0];
  float b2v[4];
  #pragma unroll
  for (int nt = 0; nt < 4; ++nt) b2v[nt] = b2s[nt * 16 + l15];

  #pragma unroll
  for (int mi = 0; mi < 2; ++mi)
    #pragma unroll
    for (int r = 0; r < 4; ++r) {
      int grow = row0 + m0 + mi * 16 + quad * 4 + r;
      float v[4]; float mx = -1e30f;
      #pragma unroll
      for (int nt = 0; nt < 4; ++nt) {
        v[nt] = acc[mi][nt][r] + b2v[nt];
        if (nt * 16 + l15 < NCLS) mx = fmaxf(mx, v[nt]);
      }
      #pragma unroll
      for (int off = 1; off < 16; off <<= 1) mx = fmaxf(mx, __shfl_xor(mx, off));
      float s = 0.f;
      #pragma unroll
      for (int nt = 0; nt < 4; ++nt)
        if (nt * 16 + l15 < NCLS) s += __expf(v[nt] - mx);
      #pragma unroll
      for (int off = 1; off < 16; off <<= 1) s += __shfl_xor(s, off);
      float den = mx + __logf(s);
      if (grow < N_NODES) {
        #pragma unroll
        for (int nt = 0; nt < 4; ++nt) {
          int c = nt * 16 + l15;
          if (c < NCLS) {
            float z = v[nt];
            out_ls [(size_t)grow * NCLS + c] = z - den;
            out_hid[(size_t)grow * NCLS + c] = t0 * z;
            cur    [(size_t)grow * CP   + c] = z;
          }
        }
      }
    }
}

// ---------------------------------------------------------------------------
// Graph prep: counts -> dis + segment starts (wave-scan + 1 atomic/wave) -> fill
// ---------------------------------------------------------------------------
__global__ void init_counts(int* counts, int* cursor)
{
  int i = blockIdx.x * 256 + threadIdx.x;
  if (i < N_NODES) counts[i] = 0;
  if (i == 0) *cursor = 0;
}

__global__ void count_edges(const int* __restrict__ col, int* __restrict__ counts)
{
  int e = blockIdx.x * 256 + threadIdx.x;
  if (e < N_EDGE) atomicAdd(&counts[col[e]], 1);
}

__global__ void dis_start(const int* __restrict__ counts, float* __restrict__ dis,
                          int* __restrict__ start, int* __restrict__ woff,
                          int* __restrict__ cursor)
{
  int i = blockIdx.x * 256 + threadIdx.x;
  int lane = threadIdx.x & 63;
  int v = (i < N_NODES) ? counts[i] : 0;
  int incl = v;
  #pragma unroll
  for (int off = 1; off < 64; off <<= 1) {
    int t = __shfl_up(incl, off);
    if (lane >= off) incl += t;
  }
  int base = 0;
  if (lane == 63) base = atomicAdd(cursor, incl);
  base = __shfl(base, 63);
  if (i < N_NODES) {
    dis[i] = rsqrtf((float)(v + 1));   // deg = in-edges + self loop
    int s = base + incl - v;
    start[i] = s;
    woff[i]  = s;
  }
}

__global__ void fill_edges(const int* __restrict__ ei, const float* __restrict__ dis,
                           int* __restrict__ woff, int2* __restrict__ edata)
{
  int e = blockIdx.x * 256 + threadIdx.x;
  if (e >= N_EDGE) return;
  int r = ei[e];
  int c = ei[N_EDGE + e];
  float w = dis[r] * dis[c];
  int pos = atomicAdd(&woff[c], 1);
  edata[pos] = make_int2(r, __float_as_int(w));
}

// ---------------------------------------------------------------------------
// One propagation step (pull): wave per dst node, lane = feature.
// nxt[d] = dis[d]^2*cur[d] + sum_{e:col==d} norm_e * cur[src_e] ;
// hid[d] += temp[k]*nxt[d]
// ---------------------------------------------------------------------------
__global__ __launch_bounds__(256) void prop_step(
    const float* __restrict__ cur, float* __restrict__ nxt,
    const float* __restrict__ dis, const int* __restrict__ start,
    const int* __restrict__ cnt, const int2* __restrict__ edata,
    float* __restrict__ hid, const float* __restrict__ temp, int kk)
{
  int wid = blockIdx.x * 4 + (threadIdx.x >> 6);
  int f   = threadIdx.x & 63;
  if (wid >= N_NODES) return;
  int fc = f < NCLS ? f : NCLS;           // lanes 47..63 clamp to pad col (no 4th line)
  float dv = dis[wid];
  float acc = dv * dv * cur[(size_t)wid * CP + fc];
  int s0 = start[wid], n = cnt[wid];
  const int2* ep = edata + s0;
  for (int j = 0; j < n; ++j) {
    int2 ed = ep[j];                      // broadcast (all lanes same addr)
    acc += __int_as_float(ed.y) * cur[(size_t)ed.x * CP + fc];
  }
  if (f < NCLS) {
    nxt[(size_t)wid * CP + f] = acc;
    hid[(size_t)wid * NCLS + f] += temp[kk] * acc;
  }
}

// ---------------------------------------------------------------------------
extern "C" void kernel_launch(void* const* d_in, const int* in_sizes, int n_in,
                              void* d_out, int out_size, void* d_ws, size_t ws_size,
                              hipStream_t stream)
{
  const float* x    = (const float*)d_in[0];
  const int*   ei   = (const int*)d_in[1];     // [2,E] int32: rows then cols
  const float* W1   = (const float*)d_in[2];
  const float* b1   = (const float*)d_in[3];
  const float* W2   = (const float*)d_in[4];
  const float* b2   = (const float*)d_in[5];
  const float* temp = (const float*)d_in[6];
  float* out_ls  = (float*)d_out;
  float* out_hid = out_ls + (size_t)N_NODES * NCLS;

  char* ws = (char*)d_ws;
  size_t off = 0;
  auto alloc = [&](size_t bytes) -> void* {
    void* p = ws + off;
    off += (bytes + 255) & ~(size_t)255;
    return p;
  };
  _Float16* h    = (_Float16*)alloc((size_t)N_NODES * HID * sizeof(_Float16));
  float* bufA    = (float*)alloc(((size_t)N_NODES * CP + 64) * sizeof(float));
  float* bufB    = (float*)alloc(((size_t)N_NODES * CP + 64) * sizeof(float));
  int*   counts  = (int*)alloc((size_t)N_NODES * sizeof(int));
  int*   startA  = (int*)alloc((size_t)N_NODES * sizeof(int));
  int*   woff    = (int*)alloc((size_t)N_NODES * sizeof(int));
  float* dis     = (float*)alloc((size_t)N_NODES * sizeof(float));
  int*   cursor  = (int*)alloc(256);
  int2*  edata   = (int2*)alloc((size_t)N_EDGE * sizeof(int2));
  (void)ws_size; (void)in_sizes; (void)n_in; (void)out_size;

  const int gemm_blocks = (N_NODES + 127) / 128;           // 782
  gemm1_relu<<<gemm_blocks, 256, 0, stream>>>(x, W1, b1, h);
  gemm2_fused<<<gemm_blocks, 256, 0, stream>>>(h, W2, b2, temp, out_ls, out_hid, bufA);
  init_counts<<<(N_NODES + 255) / 256, 256, 0, stream>>>(counts, cursor);
  count_edges<<<(N_EDGE + 255) / 256, 256, 0, stream>>>(ei + N_EDGE, counts);
  dis_start<<<(N_NODES + 255) / 256, 256, 0, stream>>>(counts, dis, startA, woff, cursor);
  fill_edges<<<(N_EDGE + 255) / 256, 256, 0, stream>>>(ei, dis, woff, edata);

  float* cur = bufA; float* nxt = bufB;
  for (int k = 0; k < K_PROP; ++k) {
    prop_step<<<(N_NODES + 3) / 4, 256, 0, stream>>>(cur, nxt, dis, startA, counts,
                                                     edata, out_hid, temp, k + 1);
    float* t = cur; cur = nxt; nxt = t;
  }
}

// Round 2
// 1651.468 us; speedup vs baseline: 2.0689x; 2.0689x over previous
//
#include <hip/hip_runtime.h>
#include <hip/hip_bf16.h>
#include <math.h>

#define N_NODES 100000
#define F_IN    500
#define HID     64
#define NCLS    47
#define CP2     64      // f16 row stride for propagation buffers: 128B = 1 cache line
#define N_EDGE  3200000
#define K_PROP  10

typedef _Float16 v8h  __attribute__((ext_vector_type(8)));
typedef float    v4f  __attribute__((ext_vector_type(4)));

// ---------------------------------------------------------------------------
// GEMM1: h[N,64] = relu(x[N,500] @ W1[500,64] + b1), f16 output for GEMM2.
// ---------------------------------------------------------------------------
__global__ __launch_bounds__(256) void gemm1_relu(
    const float* __restrict__ x, const float* __restrict__ W1,
    const float* __restrict__ b1, _Float16* __restrict__ h)
{
  __shared__ _Float16 xa[128][40];   // stride 40 f16 = 80B: 16B-aligned frags, 2-way banks
  __shared__ _Float16 wb[64][40];    // W1 tile transposed: wb[col][k]
  const int tid  = threadIdx.x;
  const int lane = tid & 63;
  const int wv   = tid >> 6;
  const int l15  = lane & 15;
  const int quad = lane >> 4;
  const int row0 = blockIdx.x * 128;

  v4f acc[2][4] = {};

  for (int k0 = 0; k0 < F_IN; k0 += 32) {
    #pragma unroll
    for (int i = 0; i < 4; ++i) {
      int f = tid + i * 256;
      int r = f >> 3, q = f & 7;
      int gr = row0 + r;
      int kk = k0 + q * 4;
      float v0 = 0.f, v1 = 0.f, v2 = 0.f, v3 = 0.f;
      if (gr < N_NODES) {
        if (kk + 3 < F_IN) {
          const float4 v = *(const float4*)(x + (size_t)gr * F_IN + kk);
          v0 = v.x; v1 = v.y; v2 = v.z; v3 = v.w;
        } else {
          const float* xp = x + (size_t)gr * F_IN;
          if (kk + 0 < F_IN) v0 = xp[kk + 0];
          if (kk + 1 < F_IN) v1 = xp[kk + 1];
          if (kk + 2 < F_IN) v2 = xp[kk + 2];
          if (kk + 3 < F_IN) v3 = xp[kk + 3];
        }
      }
      _Float16* p = &xa[r][q * 4];
      p[0] = (_Float16)v0; p[1] = (_Float16)v1;
      p[2] = (_Float16)v2; p[3] = (_Float16)v3;
    }
    #pragma unroll
    for (int i = 0; i < 2; ++i) {
      int f = tid + i * 256;
      int k = f >> 4, c4 = (f & 15) * 4;
      int gk = k0 + k;
      float4 v = make_float4(0.f, 0.f, 0.f, 0.f);
      if (gk < F_IN) v = *(const float4*)(W1 + (size_t)gk * HID + c4);
      wb[c4 + 0][k] = (_Float16)v.x; wb[c4 + 1][k] = (_Float16)v.y;
      wb[c4 + 2][k] = (_Float16)v.z; wb[c4 + 3][k] = (_Float16)v.w;
    }
    __syncthreads();
    const int m0 = wv * 32;
    v8h a0 = *(const v8h*)&xa[m0 + l15][quad * 8];
    v8h a1 = *(const v8h*)&xa[m0 + 16 + l15][quad * 8];
    #pragma unroll
    for (int nt = 0; nt < 4; ++nt) {
      v8h b = *(const v8h*)&wb[nt * 16 + l15][quad * 8];
      acc[0][nt] = __builtin_amdgcn_mfma_f32_16x16x32_f16(a0, b, acc[0][nt], 0, 0, 0);
      acc[1][nt] = __builtin_amdgcn_mfma_f32_16x16x32_f16(a1, b, acc[1][nt], 0, 0, 0);
    }
    __syncthreads();
  }
  const int m0 = wv * 32;
  float b1v[4];
  #pragma unroll
  for (int nt = 0; nt < 4; ++nt) b1v[nt] = b1[nt * 16 + l15];
  #pragma unroll
  for (int mi = 0; mi < 2; ++mi)
    #pragma unroll
    for (int r = 0; r < 4; ++r) {
      int grow = row0 + m0 + mi * 16 + quad * 4 + r;
      if (grow < N_NODES) {
        #pragma unroll
        for (int nt = 0; nt < 4; ++nt) {
          float v = fmaxf(acc[mi][nt][r] + b1v[nt], 0.f);
          h[(size_t)grow * HID + nt * 16 + l15] = (_Float16)v;
        }
      }
    }
}

// ---------------------------------------------------------------------------
// GEMM2 fused: z = h @ W2 + b2 ; out_ls = log_softmax(z) ; out_hid = temp0*z ;
// cur = z (f16, stride CP2).
// ---------------------------------------------------------------------------
__global__ __launch_bounds__(256) void gemm2_fused(
    const _Float16* __restrict__ h, const float* __restrict__ W2,
    const float* __restrict__ b2, const float* __restrict__ temp,
    float* __restrict__ out_ls, float* __restrict__ out_hid,
    _Float16* __restrict__ cur)
{
  __shared__ _Float16 ha[128][72];   // 144B rows: 16B-aligned frags
  __shared__ _Float16 wb[64][72];    // W2 transposed+padded: wb[n][k]
  __shared__ float b2s[64];
  const int tid  = threadIdx.x;
  const int lane = tid & 63;
  const int wv   = tid >> 6;
  const int l15  = lane & 15;
  const int quad = lane >> 4;
  const int row0 = blockIdx.x * 128;

  for (int i = tid; i < 64 * 72; i += 256) ((_Float16*)wb)[i] = (_Float16)0.f;
  if (tid < 64) b2s[tid] = (tid < NCLS) ? b2[tid] : 0.f;
  __syncthreads();
  for (int i = tid; i < HID * NCLS; i += 256) {
    int k = i / NCLS, n = i % NCLS;
    wb[n][k] = (_Float16)W2[i];
  }
  const unsigned short* hu = (const unsigned short*)h;
  #pragma unroll
  for (int i = 0; i < 8; ++i) {
    int f = tid + i * 256;
    int r = f >> 4, q = (f & 15) * 4;
    int gr = row0 + r;
    ushort4 v = make_ushort4(0, 0, 0, 0);
    if (gr < N_NODES) v = *(const ushort4*)(hu + (size_t)gr * HID + q);
    *(ushort4*)((unsigned short*)&ha[r][0] + q) = v;
  }
  __syncthreads();

  const int m0 = wv * 32;
  v4f acc[2][4] = {};
  #pragma unroll
  for (int ks = 0; ks < 2; ++ks) {
    v8h a0 = *(const v8h*)&ha[m0 + l15][ks * 32 + quad * 8];
    v8h a1 = *(const v8h*)&ha[m0 + 16 + l15][ks * 32 + quad * 8];
    #pragma unroll
    for (int nt = 0; nt < 4; ++nt) {
      v8h b = *(const v8h*)&wb[nt * 16 + l15][ks * 32 + quad * 8];
      acc[0][nt] = __builtin_amdgcn_mfma_f32_16x16x32_f16(a0, b, acc[0][nt], 0, 0, 0);
      acc[1][nt] = __builtin_amdgcn_mfma_f32_16x16x32_f16(a1, b, acc[1][nt], 0, 0, 0);
    }
  }

  const float t0 = temp[0];
  float b2v[4];
  #pragma unroll
  for (int nt = 0; nt < 4; ++nt) b2v[nt] = b2s[nt * 16 + l15];

  #pragma unroll
  for (int mi = 0; mi < 2; ++mi)
    #pragma unroll
    for (int r = 0; r < 4; ++r) {
      int grow = row0 + m0 + mi * 16 + quad * 4 + r;
      float v[4]; float mx = -1e30f;
      #pragma unroll
      for (int nt = 0; nt < 4; ++nt) {
        v[nt] = acc[mi][nt][r] + b2v[nt];
        if (nt * 16 + l15 < NCLS) mx = fmaxf(mx, v[nt]);
      }
      #pragma unroll
      for (int off = 1; off < 16; off <<= 1) mx = fmaxf(mx, __shfl_xor(mx, off));
      float s = 0.f;
      #pragma unroll
      for (int nt = 0; nt < 4; ++nt)
        if (nt * 16 + l15 < NCLS) s += __expf(v[nt] - mx);
      #pragma unroll
      for (int off = 1; off < 16; off <<= 1) s += __shfl_xor(s, off);
      float den = mx + __logf(s);
      if (grow < N_NODES) {
        #pragma unroll
        for (int nt = 0; nt < 4; ++nt) {
          int c = nt * 16 + l15;
          if (c < NCLS) {
            float z = v[nt];
            out_ls [(size_t)grow * NCLS + c] = z - den;
            out_hid[(size_t)grow * NCLS + c] = t0 * z;
            cur    [(size_t)grow * CP2  + c] = (_Float16)z;
          }
        }
      }
    }
}

// ---------------------------------------------------------------------------
// Graph prep
// ---------------------------------------------------------------------------
__global__ void init_counts(int* counts, int* cursor)
{
  int i = blockIdx.x * 256 + threadIdx.x;
  if (i < N_NODES) counts[i] = 0;
  if (i == 0) *cursor = 0;
}

__global__ void count_edges(const int* __restrict__ col, int* __restrict__ counts)
{
  int e = blockIdx.x * 256 + threadIdx.x;
  if (e < N_EDGE) atomicAdd(&counts[col[e]], 1);
}

__global__ void dis_start(const int* __restrict__ counts, float* __restrict__ dis,
                          int* __restrict__ start, int* __restrict__ woff,
                          int* __restrict__ cursor)
{
  int i = blockIdx.x * 256 + threadIdx.x;
  int lane = threadIdx.x & 63;
  int v = (i < N_NODES) ? counts[i] : 0;
  int incl = v;
  #pragma unroll
  for (int off = 1; off < 64; off <<= 1) {
    int t = __shfl_up(incl, off);
    if (lane >= off) incl += t;
  }
  int base = 0;
  if (lane == 63) base = atomicAdd(cursor, incl);
  base = __shfl(base, 63);
  if (i < N_NODES) {
    dis[i] = rsqrtf((float)(v + 1));   // deg = in-edges + self loop
    int s = base + incl - v;
    start[i] = s;
    woff[i]  = s;
  }
}

// edata.x = src*CP2 (pre-shifted byte-friendly index), edata.y = weight bits
__global__ void fill_edges(const int* __restrict__ ei, const float* __restrict__ dis,
                           int* __restrict__ woff, int2* __restrict__ edata)
{
  int e = blockIdx.x * 256 + threadIdx.x;
  if (e >= N_EDGE) return;
  int r = ei[e];
  int c = ei[N_EDGE + e];
  float w = dis[r] * dis[c];
  int pos = atomicAdd(&woff[c], 1);
  edata[pos] = make_int2(r << 6, __float_as_int(w));   // r*CP2
}

// ---------------------------------------------------------------------------
// One propagation step (pull): wave per dst node, lane = feature.
// 8x unrolled edge loop -> 8 independent 128B row-gathers in flight.
// ---------------------------------------------------------------------------
__global__ __launch_bounds__(256) void prop_step(
    const _Float16* __restrict__ cur, _Float16* __restrict__ nxt,
    const float* __restrict__ dis, const int* __restrict__ start,
    const int* __restrict__ cnt, const int2* __restrict__ edata,
    float* __restrict__ hid, const float* __restrict__ temp, int kk)
{
  int wid = blockIdx.x * 4 + (threadIdx.x >> 6);
  int f   = threadIdx.x & 63;
  if (wid >= N_NODES) return;
  int fc = f < NCLS ? f : NCLS;           // lanes 47..63 clamp inside the 128B row
  float dv = dis[wid];
  float acc = dv * dv * (float)cur[wid * CP2 + fc];
  int s0 = start[wid], n = cnt[wid];
  const int2* ep = edata + s0;
  int j = 0;
  for (; j + 8 <= n; j += 8) {
    int4 e0 = *(const int4*)(ep + j);       // edges j, j+1 (broadcast)
    int4 e1 = *(const int4*)(ep + j + 2);
    int4 e2 = *(const int4*)(ep + j + 4);
    int4 e3 = *(const int4*)(ep + j + 6);
    float v0 = (float)cur[e0.x + fc];
    float v1 = (float)cur[e0.z + fc];
    float v2 = (float)cur[e1.x + fc];
    float v3 = (float)cur[e1.z + fc];
    float v4 = (float)cur[e2.x + fc];
    float v5 = (float)cur[e2.z + fc];
    float v6 = (float)cur[e3.x + fc];
    float v7 = (float)cur[e3.z + fc];
    acc += __int_as_float(e0.y) * v0;
    acc += __int_as_float(e0.w) * v1;
    acc += __int_as_float(e1.y) * v2;
    acc += __int_as_float(e1.w) * v3;
    acc += __int_as_float(e2.y) * v4;
    acc += __int_as_float(e2.w) * v5;
    acc += __int_as_float(e3.y) * v6;
    acc += __int_as_float(e3.w) * v7;
  }
  for (; j < n; ++j) {
    int2 ed = ep[j];
    acc += __int_as_float(ed.y) * (float)cur[ed.x + fc];
  }
  if (f < NCLS) {
    nxt[wid * CP2 + f] = (_Float16)acc;
    hid[(size_t)wid * NCLS + f] += temp[kk] * acc;
  }
}

// ---------------------------------------------------------------------------
extern "C" void kernel_launch(void* const* d_in, const int* in_sizes, int n_in,
                              void* d_out, int out_size, void* d_ws, size_t ws_size,
                              hipStream_t stream)
{
  const float* x    = (const float*)d_in[0];
  const int*   ei   = (const int*)d_in[1];     // [2,E] int32: rows then cols
  const float* W1   = (const float*)d_in[2];
  const float* b1   = (const float*)d_in[3];
  const float* W2   = (const float*)d_in[4];
  const float* b2   = (const float*)d_in[5];
  const float* temp = (const float*)d_in[6];
  float* out_ls  = (float*)d_out;
  float* out_hid = out_ls + (size_t)N_NODES * NCLS;

  char* ws = (char*)d_ws;
  size_t off = 0;
  auto alloc = [&](size_t bytes) -> void* {
    void* p = ws + off;
    off += (bytes + 255) & ~(size_t)255;
    return p;
  };
  _Float16* h    = (_Float16*)alloc((size_t)N_NODES * HID * sizeof(_Float16));
  _Float16* bufA = (_Float16*)alloc(((size_t)N_NODES * CP2 + 64) * sizeof(_Float16));
  _Float16* bufB = (_Float16*)alloc(((size_t)N_NODES * CP2 + 64) * sizeof(_Float16));
  int*   counts  = (int*)alloc((size_t)N_NODES * sizeof(int));
  int*   startA  = (int*)alloc((size_t)N_NODES * sizeof(int));
  int*   woff    = (int*)alloc((size_t)N_NODES * sizeof(int));
  float* dis     = (float*)alloc((size_t)N_NODES * sizeof(float));
  int*   cursor  = (int*)alloc(256);
  int2*  edata   = (int2*)alloc((size_t)N_EDGE * sizeof(int2));
  (void)ws_size; (void)in_sizes; (void)n_in; (void)out_size;

  const int gemm_blocks = (N_NODES + 127) / 128;           // 782
  gemm1_relu<<<gemm_blocks, 256, 0, stream>>>(x, W1, b1, h);
  gemm2_fused<<<gemm_blocks, 256, 0, stream>>>(h, W2, b2, temp, out_ls, out_hid, bufA);
  init_counts<<<(N_NODES + 255) / 256, 256, 0, stream>>>(counts, cursor);
  count_edges<<<(N_EDGE + 255) / 256, 256, 0, stream>>>(ei + N_EDGE, counts);
  dis_start<<<(N_NODES + 255) / 256, 256, 0, stream>>>(counts, dis, startA, woff, cursor);
  fill_edges<<<(N_EDGE + 255) / 256, 256, 0, stream>>>(ei, dis, woff, edata);

  _Float16* cur = bufA; _Float16* nxt = bufB;
  for (int k = 0; k < K_PROP; ++k) {
    prop_step<<<(N_NODES + 3) / 4, 256, 0, stream>>>(cur, nxt, dis, startA, counts,
                                                     edata, out_hid, temp, k + 1);
    _Float16* t = cur; cur = nxt; nxt = t;
  }
}